// Round 9
// baseline (7703.423 us; speedup 1.0000x reference)
//
#include <hip/hip_runtime.h>
#include <stdint.h>

// Farthest point sampling, pointops semantics.
// B=8 batches, n=65536, stride=64 -> m=1024 samples/batch.
//
// Round 9: latency-hiding across chains. Each WG serves CH=4 independent
// batches ("chains"); per round it: update+publish candidates for ALL 4
// chains back-to-back (4 slot stores issue ~simultaneously from lanes 0-3),
// then poll the 4 chains in sequence. Chain 0's poll absorbs the one
// device-coherence hop H (~1.8us); chains 1-3 polls complete immediately
// after. 4 FPS steps per handshake -> ~0.55us/step instead of 2.6.
//
// Sync scheme (proven bit-exact in rounds 5-8): self-contained packed key
// (it|dist_bits|0xFFFF-idx) per WG per chain, parity-double-buffered slot
// cells, relaxed agent (sc1) stores/loads only -- no atomicMax, no acquire
// (no buffer_inv), 2 __syncthreads per round.
//
// Parity-cell safety (monotone-tag induction): slot s's parity cell for
// (c,it) is overwritten only by publish(c,it+2) from WG s, which follows WG
// s's poll(c,it+1), which requires EVERY WG to have published (c,it+1),
// which each does only after completing ALL its polls of round it. So no
// poller of (c,it) can observe the it+2 value, and no deadlock. Keys are
// single-copy-atomic 8B and self-contained (no data/flag ordering needed).
// comm is memset every launch -> graph-replay deterministic.

#define SETS 2       // groups of batches
#define CH   4       // chains (batches) per WG
#define WPB  64      // WGs per set == slots per chain == wave width
#define BS   256     // threads per WG (4 waves)
#define PPT  4       // points per thread per chain
#define SLICE (BS * PPT)   // 1024 points per WG per chain

typedef unsigned long long u64;
typedef unsigned int u32;

// key layout: [63:48]=it  [47:16]=float bits of best dist (nonneg)
//             [15:0]=0xFFFF-idx  (bigger wins => smaller idx wins ties,
//             numpy argmax first-max semantics; nonneg IEEE floats compare
//             like their bit patterns)

__global__ __launch_bounds__(BS, 1)
void fps_mc(const float* __restrict__ p, int n, int m,
            u64* __restrict__ comm,
            float* __restrict__ out_np, float* __restrict__ out_no,
            float* __restrict__ out_idx)
{
#pragma clang fp contract(off)
    const int bg   = blockIdx.x;
    const int set  = bg / WPB;
    const int g    = bg % WPB;
    const int t    = threadIdx.x;
    const int lane = t & 63;
    const int w    = t >> 6;

    // coords, float4-transposed per chain: sX[c][t] = x of pts (t*PPT..+3)
    __shared__ float4 sX[CH][BS], sY[CH][BS], sZ[CH][BS];   // 48 KB
    __shared__ float s_val[CH][BS / 64];
    __shared__ int   s_idx[CH][BS / 64];
    __shared__ float s_q[CH][3];

    // ---- stage all 4 chains' slices into LDS (one-time) ----
#pragma unroll
    for (int c = 0; c < CH; ++c) {
        const int b = set * CH + c;
        const float4* pb4 =
            (const float4*)(p + 3ull * (u32)(b * n + g * SLICE + t * PPT));
        float cf[12];
#pragma unroll
        for (int v = 0; v < 3; ++v) {
            float4 f = pb4[v];
            cf[4 * v + 0] = f.x; cf[4 * v + 1] = f.y;
            cf[4 * v + 2] = f.z; cf[4 * v + 3] = f.w;
        }
        sX[c][t] = make_float4(cf[0], cf[3], cf[6], cf[9]);
        sY[c][t] = make_float4(cf[1], cf[4], cf[7], cf[10]);
        sZ[c][t] = make_float4(cf[2], cf[5], cf[8], cf[11]);
    }
    __syncthreads();

    float dist[CH][PPT];
#pragma unroll
    for (int c = 0; c < CH; ++c)
#pragma unroll
        for (int j = 0; j < PPT; ++j) dist[c][j] = 1e10f;

    // first query of each chain = point 0 of its batch
    float qx[CH], qy[CH], qz[CH];
#pragma unroll
    for (int c = 0; c < CH; ++c) {
        const float* q0 = p + 3ull * (u32)((set * CH + c) * n);
        qx[c] = q0[0]; qy[c] = q0[1]; qz[c] = q0[2];
    }
    if (g == 0 && t == 0) {
#pragma unroll
        for (int c = 0; c < CH; ++c) {
            int b = set * CH + c;
            out_idx[(size_t)b * m] = (float)(b * n);
            out_np[(size_t)(b * m) * 3 + 0] = qx[c];
            out_np[(size_t)(b * m) * 3 + 1] = qy[c];
            out_np[(size_t)(b * m) * 3 + 2] = qz[c];
            out_no[b] = (float)((b + 1) * m);
        }
    }

    // per-set comm: CH chains x 2 parities x WPB slots (u64)
    u64* cb = comm + (size_t)set * (CH * 2 * WPB);

    for (int it = 1; it < m; ++it) {
        const int par = it & 1;
        // block cross-iteration caching of LDS reads (round-6 spill trap)
        asm volatile("" ::: "memory");

        // ---- update + per-thread + per-wave argmax, ALL 4 chains ----
#pragma unroll
        for (int c = 0; c < CH; ++c) {
            float4 X = sX[c][t], Y = sY[c][t], Z = sZ[c][t];
            float xl[4] = {X.x, X.y, X.z, X.w};
            float yl[4] = {Y.x, Y.y, Y.z, Y.w};
            float zl[4] = {Z.x, Z.y, Z.z, Z.w};
            float best = -1.0f;
            int   bj   = 0;
#pragma unroll
            for (int e = 0; e < PPT; ++e) {
                float dx = xl[e] - qx[c];
                float dy = yl[e] - qy[c];
                float dz = zl[e] - qz[c];
                float d  = dx * dx + dy * dy + dz * dz; // contract off: left-assoc
                float nd = fminf(dist[c][e], d);
                dist[c][e] = nd;
                if (nd > best) { best = nd; bj = e; }   // strict >: earliest wins
            }
            int bidx = g * SLICE + t * PPT + bj;        // batch-local winner idx
#pragma unroll
            for (int off = 1; off < 64; off <<= 1) {
                float ov = __shfl_xor(best, off);
                int   oi = __shfl_xor(bidx, off);
                if (ov > best || (ov == best && oi < bidx)) { best = ov; bidx = oi; }
            }
            if (lane == 0) { s_val[c][w] = best; s_idx[c][w] = bidx; }
        }
        __syncthreads();                                 // barrier #1

        // ---- lanes 0..3 of wave 0: reduce + publish chain 'lane' ----
        if (w == 0 && lane < CH) {
            float v = -1.0f; int ix = 0x7fffffff;
#pragma unroll
            for (int ww = 0; ww < BS / 64; ++ww) {
                float sv = s_val[lane][ww]; int si = s_idx[lane][ww];
                if (sv > v || (sv == v && si < ix)) { v = sv; ix = si; }
            }
            u64 k = ((u64)(u32)it << 48)
                  | ((u64)(u32)__float_as_uint(v) << 16)
                  | (u64)(u32)(0xFFFF - ix);
            __hip_atomic_store(cb + (size_t)(lane * 2 + par) * WPB + g, k,
                               __ATOMIC_RELAXED, __HIP_MEMORY_SCOPE_AGENT);
        }

        // ---- wave 0: poll chains in sequence (all publishes already out) ----
        if (w == 0) {
            int   kidx[CH];
            float qlx[CH], qly[CH], qlz[CH];
#pragma unroll
            for (int c = 0; c < CH; ++c) {
                u64* sb = cb + (size_t)(c * 2 + par) * WPB;
                u64 k; bool ok;
                do {
                    k  = __hip_atomic_load(sb + lane, __ATOMIC_RELAXED,
                                           __HIP_MEMORY_SCOPE_AGENT);
                    ok = ((u32)(k >> 48) == (u32)it);
                } while (!__all(ok));
                // wave max over 64 keys: (it,dist,-idx) lexicographic
#pragma unroll
                for (int off = 1; off < 64; off <<= 1) {
                    u64 k2 = __shfl_xor(k, off);
                    if (k2 > k) k = k2;
                }
                int ki = 0xFFFF - (int)(k & 0xFFFF);
                kidx[c] = ki;
                if (lane == 0) {
                    // issue winner-coords load now; latency hides under the
                    // next chain's poll loop
                    const float* wp = p + 3ull * (u32)((set * CH + c) * n + ki);
                    qlx[c] = wp[0]; qly[c] = wp[1]; qlz[c] = wp[2];
                }
            }
            if (lane == 0) {
#pragma unroll
                for (int c = 0; c < CH; ++c) {
                    s_q[c][0] = qlx[c]; s_q[c][1] = qly[c]; s_q[c][2] = qlz[c];
                }
                if (g == 0) {
#pragma unroll
                    for (int c = 0; c < CH; ++c) {
                        int b = set * CH + c;
                        out_idx[(size_t)b * m + it] = (float)(b * n + kidx[c]);
                        out_np[(size_t)(b * m + it) * 3 + 0] = qlx[c];
                        out_np[(size_t)(b * m + it) * 3 + 1] = qly[c];
                        out_np[(size_t)(b * m + it) * 3 + 2] = qlz[c];
                    }
                }
            }
        }
        __syncthreads();                                 // barrier #2
#pragma unroll
        for (int c = 0; c < CH; ++c) {
            qx[c] = s_q[c][0]; qy[c] = s_q[c][1]; qz[c] = s_q[c][2];
        }
    }
}

extern "C" void kernel_launch(void* const* d_in, const int* in_sizes, int n_in,
                              void* d_out, int out_size, void* d_ws, size_t ws_size,
                              hipStream_t stream) {
    const float* p = (const float*)d_in[0];
    int N = in_sizes[0] / 3;           // 524288
    int B = in_sizes[1];               // 8
    int n = N / B;                     // 65536
    int m = (out_size / B - 1) / 4;    // 1024

    float* out_np  = (float*)d_out;
    float* out_no  = out_np + (size_t)B * m * 3;
    float* out_idx = out_no + B;

    u64* comm = (u64*)d_ws;
    // clear all slot cells every launch (graph-safe, replay-deterministic)
    hipMemsetAsync(d_ws, 0, (size_t)SETS * CH * 2 * WPB * sizeof(u64), stream);

    fps_mc<<<SETS * WPB, BS, 0, stream>>>(p, n, m, comm,
                                          out_np, out_no, out_idx);
}

// Round 10
// 2534.011 us; speedup vs baseline: 3.0400x; 3.0400x over previous
//
#include <hip/hip_runtime.h>
#include <stdint.h>

// Farthest point sampling, pointops semantics.
// B=8 batches, n=65536, stride=64 -> m=1024 samples/batch.
//
// Round 10 = round 8 structure (16 WGs/batch, coords in LDS float4, packed
// self-contained keys, parity-double-buffered slots, 2 barriers/step) with a
// DUAL-DOMAIN handshake:
//   - batch = blockIdx%8: with the CP's round-robin XCD assignment, all 16
//     WGs of a batch share one XCD (and its coherent L2).
//   - publisher stores its key to an sc0 cell (XCD-L2 domain, ~250cy RTT)
//     AND an sc1 cell (device domain, guaranteed) -- separate cachelines.
//   - wave 0 polls sc0 cells with a BOUNDED loop; success => stay in sc0
//     mode (sticky); expiry => permanently demote to unbounded sc1 polling.
// If the placement assumption (or sc0 semantics) fails, every WG burns the
// budget once and then runs exactly like round 8. No spin ever depends on
// unproven visibility: the sc1 copy always exists. => deadlock-free.
//
// Parity-cell safety (monotone-tag induction, per copy): slot s's parity
// cell for step it is overwritten only by publish(it+2) from WG s, which
// follows WG s's poll(it+1), which requires EVERY WG to have published
// it+1, which each does only after completing its poll(it) (either path).
// Keys are 8B single-copy-atomic and self-contained. comm is memset every
// launch; kernel-dispatch boundaries flush/invalidate device caches, so no
// stale sc0 lines survive across graph replays.

#define G      16    // workgroups per batch
#define BS     256   // threads per workgroup (4 waves)
#define PPT    16    // points per thread (G*BS*PPT == n)
#define NC     (PPT/4)
#define NBATCH 8
#define SC0_BUDGET 2048

typedef unsigned long long u64;
typedef unsigned int u32;

// key layout: [63:48]=it  [47:16]=float bits of best dist (nonneg)
//             [15:0]=0xFFFF-idx  (bigger wins => smaller idx wins ties,
//             numpy argmax first-max semantics; nonneg IEEE floats compare
//             like their bit patterns)

__global__ __launch_bounds__(BS, 1)
void fps_xcd(const float* __restrict__ p, int n, int m,
             u64* __restrict__ comm,
             float* __restrict__ out_np, float* __restrict__ out_no,
             float* __restrict__ out_idx)
{
#pragma clang fp contract(off)
    const int bg   = blockIdx.x;
    const int b    = bg & (NBATCH - 1);  // %8: co-XCD under round-robin CP
    const int g    = bg >> 3;            // 0..15 within batch
    const int t    = threadIdx.x;
    const int lane = t & 63;
    const int w    = t >> 6;
    const int gbase  = b * n;            // global point base of this batch
    const int wgbase = g * (BS * PPT);   // batch-local base of this WG

    __shared__ float4 xs[NC * BS], ys[NC * BS], zs[NC * BS];   // 48 KB
    __shared__ float s_val[BS / 64];
    __shared__ int   s_idx[BS / 64];
    __shared__ int   s_k;

    int mode = 0;   // 0 = sc0 (XCD-L2) polling, 1 = sc1 (device) polling

    // ---- stage coords into LDS (one-time; 12 float4 global loads) ----
    {
        const float4* pb = (const float4*)(p + 3ull * (u32)(gbase + wgbase + t * PPT));
        float c[12 * 4];
#pragma unroll
        for (int v = 0; v < 12; ++v) {
            float4 f = pb[v];
            c[4 * v + 0] = f.x; c[4 * v + 1] = f.y; c[4 * v + 2] = f.z; c[4 * v + 3] = f.w;
        }
#pragma unroll
        for (int cc = 0; cc < NC; ++cc) {
            float4 X, Y, Z;
            X.x = c[(cc * 4 + 0) * 3 + 0]; X.y = c[(cc * 4 + 1) * 3 + 0];
            X.z = c[(cc * 4 + 2) * 3 + 0]; X.w = c[(cc * 4 + 3) * 3 + 0];
            Y.x = c[(cc * 4 + 0) * 3 + 1]; Y.y = c[(cc * 4 + 1) * 3 + 1];
            Y.z = c[(cc * 4 + 2) * 3 + 1]; Y.w = c[(cc * 4 + 3) * 3 + 1];
            Z.x = c[(cc * 4 + 0) * 3 + 2]; Z.y = c[(cc * 4 + 1) * 3 + 2];
            Z.z = c[(cc * 4 + 2) * 3 + 2]; Z.w = c[(cc * 4 + 3) * 3 + 2];
            xs[cc * BS + t] = X; ys[cc * BS + t] = Y; zs[cc * BS + t] = Z;
        }
    }
    __syncthreads();

    float dist[PPT];
#pragma unroll
    for (int j = 0; j < PPT; ++j) dist[j] = 1e10f;

    // first query = point 0 of the batch
    float qx = p[3ull * (u32)gbase + 0];
    float qy = p[3ull * (u32)gbase + 1];
    float qz = p[3ull * (u32)gbase + 2];

    if (g == 0 && t == 0) {
        out_idx[(size_t)b * m] = (float)gbase;
        out_np[(size_t)(b * m) * 3 + 0] = qx;
        out_np[(size_t)(b * m) * 3 + 1] = qy;
        out_np[(size_t)(b * m) * 3 + 2] = qz;
        out_no[b] = (float)((b + 1) * m);
    }

    // per-batch comm: 2 parities x { 16 sc0 cells | 16 sc1 cells } (512 B)
    u64* cb = comm + (size_t)b * 64;

    for (int it = 1; it < m; ++it) {
        // stop LDS values from being promoted/cached across steps
        asm volatile("" ::: "memory");

        // ---- local distance update + per-thread argmax (ids ascend in j) ----
        float best = -1.0f;
        int   bj   = 0;
#pragma unroll
        for (int cc = 0; cc < NC; ++cc) {
            float4 X = xs[cc * BS + t];
            float4 Y = ys[cc * BS + t];
            float4 Z = zs[cc * BS + t];
            float xl[4] = {X.x, X.y, X.z, X.w};
            float yl[4] = {Y.x, Y.y, Y.z, Y.w};
            float zl[4] = {Z.x, Z.y, Z.z, Z.w};
#pragma unroll
            for (int e = 0; e < 4; ++e) {
                float dx = xl[e] - qx;
                float dy = yl[e] - qy;
                float dz = zl[e] - qz;
                float d  = dx * dx + dy * dy + dz * dz;  // contract off: left-assoc
                int j = cc * 4 + e;
                float nd = fminf(dist[j], d);
                dist[j] = nd;
                if (nd > best) { best = nd; bj = j; }    // strict > keeps earliest
            }
        }
        int bidx = wgbase + t * PPT + bj;                // batch-local winner idx

        // ---- wave argmax (64 lanes; ids ascend with lane) ----
#pragma unroll
        for (int off = 1; off < 64; off <<= 1) {
            float ov = __shfl_xor(best, off);
            int   oi = __shfl_xor(bidx, off);
            if (ov > best || (ov == best && oi < bidx)) { best = ov; bidx = oi; }
        }
        if (lane == 0) { s_val[w] = best; s_idx[w] = bidx; }
        __syncthreads();                                  // barrier #1

        u64* sb = cb + (size_t)(it & 1) * 32;             // this parity's cells

        if (w == 0) {
            // ---- lane 0: WG reduce + dual publish (sc0 + sc1 copies) ----
            if (lane == 0) {
                float v = -1.0f; int ix = 0x7fffffff;
#pragma unroll
                for (int ww = 0; ww < BS / 64; ++ww) {
                    if (s_val[ww] > v || (s_val[ww] == v && s_idx[ww] < ix)) {
                        v = s_val[ww]; ix = s_idx[ww];
                    }
                }
                u64 kk = ((u64)(u32)it << 48)
                       | ((u64)(u32)__float_as_uint(v) << 16)
                       | (u64)(u32)(0xFFFF - ix);
                u64* c0 = sb + g;        // sc0 cell (XCD-L2 domain)
                asm volatile("global_store_dwordx2 %0, %1, off sc0"
                             :: "v"(c0), "v"(kk) : "memory");
                __hip_atomic_store(sb + 16 + g, kk, __ATOMIC_RELAXED,
                                   __HIP_MEMORY_SCOPE_AGENT);   // sc1 cell
            }

            // ---- poll: bounded sc0 fast path, sticky demotion to sc1 ----
            u64 k = 0;
            bool done = false;
            if (mode == 0) {
                int tries = 0;
                do {
                    bool ok = true;
                    if (lane < G) {
                        u64 kk;
                        asm volatile("global_load_dwordx2 %0, %1, off sc0\n\t"
                                     "s_waitcnt vmcnt(0)"
                                     : "=v"(kk) : "v"(sb + lane) : "memory");
                        k  = kk;
                        ok = ((u32)(kk >> 48) == (u32)it);
                    }
                    done = __all(ok);
                } while (!done && ++tries < SC0_BUDGET);
                if (!done) mode = 1;     // sticky: sc1-only from now on
            }
            if (!done) {
                // guaranteed path: relaxed agent (sc1) loads on the sc1 cells
                bool ok;
                do {
                    ok = true;
                    if (lane < G) {
                        k  = __hip_atomic_load(sb + 16 + lane, __ATOMIC_RELAXED,
                                               __HIP_MEMORY_SCOPE_AGENT);
                        ok = ((u32)(k >> 48) == (u32)it);
                    }
                } while (!__all(ok));
            }

            // ---- max over 16 keys (xor stages stay within 16-lane group) ----
#pragma unroll
            for (int off = 1; off < G; off <<= 1) {
                u64 k2 = __shfl_xor(k, off);
                if (k2 > k) k = k2;
            }
            if (lane == 0) s_k = 0xFFFF - (int)(k & 0xFFFF);
        }
        __syncthreads();                                  // barrier #2
        int kidx = s_k;

        // winner coords from read-only p (L1/L2-warm: loop has no cache-inv)
        const float* wp = p + 3ull * (u32)(gbase + kidx);
        qx = wp[0]; qy = wp[1]; qz = wp[2];

        if (g == 0 && t == 0) {
            out_idx[(size_t)b * m + it] = (float)(gbase + kidx);
            out_np[(size_t)(b * m + it) * 3 + 0] = qx;
            out_np[(size_t)(b * m + it) * 3 + 1] = qy;
            out_np[(size_t)(b * m + it) * 3 + 2] = qz;
        }
    }
}

extern "C" void kernel_launch(void* const* d_in, const int* in_sizes, int n_in,
                              void* d_out, int out_size, void* d_ws, size_t ws_size,
                              hipStream_t stream) {
    const float* p = (const float*)d_in[0];
    int N = in_sizes[0] / 3;           // 524288
    int B = in_sizes[1];               // 8
    int n = N / B;                     // 65536
    int m = (out_size / B - 1) / 4;    // 1024

    float* out_np  = (float*)d_out;
    float* out_no  = out_np + (size_t)B * m * 3;
    float* out_idx = out_no + B;

    u64* comm = (u64*)d_ws;
    // clear all slot cells (both copies, both parities) every launch
    hipMemsetAsync(d_ws, 0, (size_t)NBATCH * 64 * sizeof(u64), stream);

    fps_xcd<<<NBATCH * G, BS, 0, stream>>>(p, n, m, comm,
                                           out_np, out_no, out_idx);
}